// Round 12
// baseline (243.472 us; speedup 1.0000x reference)
//
#include <hip/hip_runtime.h>
#include <cstddef>
#include <cstdint>

// MambaDoc — round 12 (R11 + three targeted cuts):
//  * inproj grid (6,128): dt columns via per-thread dot in block x==5
//    (saves 1/7 of the biggest GEMM's MFMA+staging)
//  * outrms: rstd sum-of-squares folded into GEMM staging (prologue pass gone)
//  * ssd_ph: Hin fragments prefetched into VGPRs at kernel start
//    (Hin LDS staging round + barrier deleted)

#define LSEQ 4096
#define MTOK 16384

typedef unsigned short u16;
typedef _Float16 f16x8 __attribute__((ext_vector_type(8)));
typedef float f32x4 __attribute__((ext_vector_type(4)));

__device__ __forceinline__ u16 f2h(float x) {
    return __builtin_bit_cast(u16, (_Float16)x);
}
__device__ __forceinline__ float h2f(u16 u) {
    return (float)__builtin_bit_cast(_Float16, u);
}
__device__ __forceinline__ float silu_f(float x) { return x / (1.f + __expf(-x)); }

__device__ __forceinline__ void async_lds16(const void* g, void* l) {
    __builtin_amdgcn_global_load_lds(
        (const __attribute__((address_space(1))) unsigned int*)g,
        (__attribute__((address_space(3))) unsigned int*)l, 16, 0, 0);
}

__device__ __forceinline__ uint4 cvt8(const float* __restrict__ src) {
    float4 a = *(const float4*)src;
    float4 b = *(const float4*)(src + 4);
    union { u16 u[8]; uint4 q; } pk;
    pk.u[0] = f2h(a.x); pk.u[1] = f2h(a.y); pk.u[2] = f2h(a.z); pk.u[3] = f2h(a.w);
    pk.u[4] = f2h(b.x); pk.u[5] = f2h(b.y); pk.u[6] = f2h(b.z); pk.u[7] = f2h(b.w);
    return pk.q;
}

__device__ __forceinline__ uint4 cvt8g(const float* __restrict__ src,
                                       const float* __restrict__ gw) {
    float4 a = *(const float4*)src;
    float4 b = *(const float4*)(src + 4);
    float4 ga = *(const float4*)gw;
    float4 gb = *(const float4*)(gw + 4);
    union { u16 u[8]; uint4 q; } pk;
    pk.u[0] = f2h(a.x * ga.x); pk.u[1] = f2h(a.y * ga.y);
    pk.u[2] = f2h(a.z * ga.z); pk.u[3] = f2h(a.w * ga.w);
    pk.u[4] = f2h(b.x * gb.x); pk.u[5] = f2h(b.y * gb.y);
    pk.u[6] = f2h(b.z * gb.z); pk.u[7] = f2h(b.w * gb.w);
    return pk.q;
}

// ---------------------------------------------------------------------------
// Initial projection + fused RMSNorm. BM=64, grid (1,256).
// ---------------------------------------------------------------------------
__global__ __launch_bounds__(256) void gemm_rms0_kernel(
    const float* __restrict__ xf, const float* __restrict__ wf,
    const float* __restrict__ bias, const float* __restrict__ rmsw,
    u16* __restrict__ xp16, u16* __restrict__ hbuf16, u16* __restrict__ hn16)
{
    __shared__ u16 sA[64 * 64];
    __shared__ u16 sW[128 * 64];
    __shared__ float red[64][33];
    __shared__ float srstd[64];
    const int m0 = blockIdx.y * 64;
    const int tid = threadIdx.x, wid = tid >> 6, lane = tid & 63;
    const int wm = (wid >> 1) * 32, wn = (wid & 1) * 64;
    const int quad = lane >> 4, cl = lane & 15;
    #pragma unroll
    for (int i = 0; i < 2; i++) {
        int ck = i * 256 + tid;
        int r = ck >> 3, cc = ck & 7;
        int csw = (cc ^ (r & 7)) << 3;
        *(uint4*)&sA[ck * 8] = cvt8(xf + (size_t)(m0 + r) * 64 + csw);
    }
    #pragma unroll
    for (int i = 0; i < 4; i++) {
        int ck = i * 256 + tid;
        int r = ck >> 3, cc = ck & 7;
        int csw = (cc ^ (r & 7)) << 3;
        *(uint4*)&sW[ck * 8] = cvt8(wf + (size_t)r * 64 + csw);
    }
    __syncthreads();
    f32x4 acc[2][4];
    #pragma unroll
    for (int i = 0; i < 2; i++)
        #pragma unroll
        for (int j = 0; j < 4; j++) acc[i][j] = f32x4{0.f, 0.f, 0.f, 0.f};
    #pragma unroll
    for (int ks = 0; ks < 2; ks++) {
        f16x8 af[2], wv[4];
        int kc = ks * 4 + quad;
        #pragma unroll
        for (int i = 0; i < 2; i++) {
            int r = wm + i * 16 + cl;
            af[i] = *(const f16x8*)&sA[r * 64 + ((kc ^ (r & 7)) << 3)];
        }
        #pragma unroll
        for (int j = 0; j < 4; j++) {
            int r = wn + j * 16 + cl;
            wv[j] = *(const f16x8*)&sW[r * 64 + ((kc ^ (r & 7)) << 3)];
        }
        #pragma unroll
        for (int i = 0; i < 2; i++)
            #pragma unroll
            for (int j = 0; j < 4; j++)
                acc[i][j] = __builtin_amdgcn_mfma_f32_16x16x32_f16(
                    af[i], wv[j], acc[i][j], 0, 0, 0);
    }
    const int slot = (wid & 1) * 16 + cl;
    #pragma unroll
    for (int i = 0; i < 2; i++)
        #pragma unroll
        for (int r = 0; r < 4; r++) {
            int t = wm + i * 16 + quad * 4 + r;
            float ssp = 0.f;
            #pragma unroll
            for (int j = 0; j < 4; j++) {
                int n = wn + j * 16 + cl;
                float v = acc[i][j][r] + bias[n];
                acc[i][j][r] = v;
                ssp += v * v;
            }
            red[t][slot] = ssp;
        }
    __syncthreads();
    if (tid < 64) {
        float s = 0.f;
        #pragma unroll
        for (int sl = 0; sl < 32; sl++) s += red[tid][sl];
        srstd[tid] = rsqrtf(s * (1.f / 128.f) + 1e-5f);
    }
    __syncthreads();
    #pragma unroll
    for (int i = 0; i < 2; i++)
        #pragma unroll
        for (int r = 0; r < 4; r++) {
            int t = wm + i * 16 + quad * 4 + r;
            size_t ob = (size_t)(m0 + t) * 128;
            float rstd = srstd[t];
            #pragma unroll
            for (int j = 0; j < 4; j++) {
                int n = wn + j * 16 + cl;
                float v = acc[i][j][r];
                u16 vh = f2h(v);
                xp16[ob + n] = vh;
                hbuf16[ob + n] = vh;
                hn16[ob + n] = f2h(v * rstd * rmsw[n]);
            }
        }
}

// ---------------------------------------------------------------------------
// in_proj GEMM fp16 (K=128). Grid (6, 128) — 768 GEMM columns; block x==5
// additionally computes the 2 dt columns via per-thread dot + cumsum.
// ---------------------------------------------------------------------------
__global__ __launch_bounds__(256) void gemm_inproj_kernel(
    const u16* __restrict__ A, const float* __restrict__ Wf,
    u16* __restrict__ zx16, float* __restrict__ dtb, float* __restrict__ Sb,
    const float* __restrict__ dt_bias, const float* __restrict__ A_log)
{
    __shared__ u16 sA[128 * 64];
    __shared__ u16 sW[128 * 64];
    __shared__ float sdt[2][128];
    const int K = 128;
    const int n0 = blockIdx.x * 128, m0 = blockIdx.y * 128;
    const int tid = threadIdx.x, wid = tid >> 6, lane = tid & 63;
    const int wm = (wid >> 1) * 64, wn = (wid & 1) * 64;
    const int quad = lane >> 4, cl = lane & 15;
    f32x4 acc[4][4];
    #pragma unroll
    for (int i = 0; i < 4; i++)
        #pragma unroll
        for (int j = 0; j < 4; j++) acc[i][j] = f32x4{0.f, 0.f, 0.f, 0.f};

    for (int k0 = 0; k0 < K; k0 += 64) {
        #pragma unroll
        for (int i = 0; i < 4; i++) {
            int ck = i * 256 + tid;
            int r = ck >> 3, cc = ck & 7;
            int csw = (cc ^ (r & 7)) << 3;
            async_lds16(A + (size_t)(m0 + r) * K + k0 + csw,
                        (void*)(sA + (i * 256 + (tid & ~63)) * 8));
        }
        #pragma unroll
        for (int i = 0; i < 4; i++) {
            int ck = i * 256 + tid;
            int r = ck >> 3, cc = ck & 7;
            int csw = (cc ^ (r & 7)) << 3;
            *(uint4*)&sW[ck * 8] = cvt8(Wf + (size_t)(n0 + r) * K + k0 + csw);
        }
        __syncthreads();
        #pragma unroll
        for (int ks = 0; ks < 2; ks++) {
            f16x8 af[4], wv[4];
            int kc = ks * 4 + quad;
            #pragma unroll
            for (int i = 0; i < 4; i++) {
                int r = wm + i * 16 + cl;
                af[i] = *(const f16x8*)&sA[r * 64 + ((kc ^ (r & 7)) << 3)];
            }
            #pragma unroll
            for (int j = 0; j < 4; j++) {
                int r = wn + j * 16 + cl;
                wv[j] = *(const f16x8*)&sW[r * 64 + ((kc ^ (r & 7)) << 3)];
            }
            #pragma unroll
            for (int i = 0; i < 4; i++)
                #pragma unroll
                for (int j = 0; j < 4; j++)
                    acc[i][j] = __builtin_amdgcn_mfma_f32_16x16x32_f16(
                        af[i], wv[j], acc[i][j], 0, 0, 0);
        }
        __syncthreads();
    }
    #pragma unroll
    for (int i = 0; i < 4; i++) {
        int m = m0 + wm + i * 16 + quad * 4;
        #pragma unroll
        for (int j = 0; j < 4; j++) {
            int n = n0 + wn + j * 16 + cl;
            #pragma unroll
            for (int r = 0; r < 4; r++)
                zx16[(size_t)(m + r) * 768 + n] = f2h(acc[i][j][r]);
        }
    }
    if (blockIdx.x == 5) {
        // dt columns 768/769: per-thread dot (fp16 A x fp32 W) + softplus +
        // chunk-local cumsum.
        const int t = tid >> 1, hh = tid & 1;
        const u16* arow = A + (size_t)(m0 + t) * 128;
        const float* wrow = Wf + (size_t)(768 + hh) * 128;
        float dot = 0.f;
        #pragma unroll
        for (int k = 0; k < 128; k += 8) {
            f16x8 av = *(const f16x8*)&arow[k];
            #pragma unroll
            for (int j = 0; j < 8; j++) dot += (float)av[j] * wrow[k + j];
        }
        float rawv = dot + dt_bias[hh];
        float dt = fmaxf(rawv, 0.f) + log1pf(__expf(-fabsf(rawv)));
        dtb[(size_t)(m0 + t) * 2 + hh] = dt;
        float ad = -__expf(A_log[hh]) * dt;
        __syncthreads();
        sdt[hh][t] = ad;
        __syncthreads();
        for (int off = 1; off < 128; off <<= 1) {
            float add = (t >= off) ? sdt[hh][t - off] : 0.f;
            __syncthreads();
            sdt[hh][t] += add;
            __syncthreads();
        }
        Sb[(size_t)(m0 + t) * 2 + hh] = sdt[hh][t];
    }
}

// ---------------------------------------------------------------------------
// chunkstate + inlined conv. Grid (32,2,4), 512 thr.
// ---------------------------------------------------------------------------
__global__ __launch_bounds__(512) void chunkstate_conv_kernel(
    const u16* __restrict__ zx16, const float* __restrict__ cw,
    const float* __restrict__ cb, const float* __restrict__ dtb,
    const float* __restrict__ Sb, u16* __restrict__ Hb)
{
    __shared__ u16 raw[2560 * 8];
    __shared__ u16 XT[128 * 128];
    __shared__ u16 BT[128 * 128];
    __shared__ float scw[2][128][4];
    __shared__ float scb[2][128];
    __shared__ float ssw[128];
    const int c = blockIdx.x, h = blockIdx.y, b = blockIdx.z;
    const int tid = threadIdx.x, wid = tid >> 6, lane = tid & 63;
    const int quad = lane >> 4, cl = lane & 15;
    const int tok0 = b * LSEQ + c * 128;
    for (int idx = tid; idx < 256; idx += 512) {
        int grp = idx >> 7, j = idx & 127;
        int ch = grp ? (256 + j) : (128 * h + j);
        float4 w4 = *(const float4*)&cw[ch * 4];
        scw[grp][j][0] = w4.x; scw[grp][j][1] = w4.y;
        scw[grp][j][2] = w4.z; scw[grp][j][3] = w4.w;
        scb[grp][j] = cb[ch];
    }
    if (tid < 128) {
        float Sl = Sb[(size_t)(tok0 + 127) * 2 + h];
        ssw[tid] = __expf(Sl - Sb[(size_t)(tok0 + tid) * 2 + h])
                   * dtb[(size_t)(tok0 + tid) * 2 + h];
    }
    #pragma unroll
    for (int i = 0; i < 5; i++) {
        int ck = i * 512 + tid;
        int r = ck >> 4; if (r > 130) r = 130;
        int cc = ck & 15;
        int tok = tok0 - 3 + r; if (tok < 0) tok = 0;
        async_lds16(zx16 + (size_t)tok * 768 + 256 + 128 * h + ((cc ^ (r & 15)) << 3),
                    (void*)(raw + (i * 512 + (tid & ~63)) * 8));
    }
    __syncthreads();
    if (c == 0 && tid < 48) *(uint4*)&raw[tid * 8] = make_uint4(0, 0, 0, 0);
    __syncthreads();
    #pragma unroll
    for (int it = 0; it < 4; it++) {
        int idx = it * 512 + tid;
        int s = idx & 127, pg = idx >> 7;
        f16x8 v[4];
        #pragma unroll
        for (int k = 0; k < 4; k++) {
            int rr = s + k;
            v[k] = *(const f16x8*)&raw[rr * 128 + ((pg ^ (rr & 15)) << 3)];
        }
        #pragma unroll
        for (int j = 0; j < 8; j++) {
            int p = pg * 8 + j;
            float o = scb[0][p] + (float)v[0][j] * scw[0][p][0]
                    + (float)v[1][j] * scw[0][p][1]
                    + (float)v[2][j] * scw[0][p][2]
                    + (float)v[3][j] * scw[0][p][3];
            o = silu_f(o);
            XT[p * 128 + (((s >> 3) ^ (p & 15)) << 3) + (s & 7)] = f2h(o);
        }
    }
    __syncthreads();
    #pragma unroll
    for (int i = 0; i < 5; i++) {
        int ck = i * 512 + tid;
        int r = ck >> 4; if (r > 130) r = 130;
        int cc = ck & 15;
        int tok = tok0 - 3 + r; if (tok < 0) tok = 0;
        async_lds16(zx16 + (size_t)tok * 768 + 512 + ((cc ^ (r & 15)) << 3),
                    (void*)(raw + (i * 512 + (tid & ~63)) * 8));
    }
    __syncthreads();
    if (c == 0 && tid < 48) *(uint4*)&raw[tid * 8] = make_uint4(0, 0, 0, 0);
    __syncthreads();
    #pragma unroll
    for (int it = 0; it < 4; it++) {
        int idx = it * 512 + tid;
        int s = idx & 127, ng = idx >> 7;
        f16x8 v[4];
        #pragma unroll
        for (int k = 0; k < 4; k++) {
            int rr = s + k;
            v[k] = *(const f16x8*)&raw[rr * 128 + ((ng ^ (rr & 15)) << 3)];
        }
        float wsv = ssw[s];
        #pragma unroll
        for (int j = 0; j < 8; j++) {
            int n = ng * 8 + j;
            float o = scb[1][n] + (float)v[0][j] * scw[1][n][0]
                    + (float)v[1][j] * scw[1][n][1]
                    + (float)v[2][j] * scw[1][n][2]
                    + (float)v[3][j] * scw[1][n][3];
            o = silu_f(o) * wsv;
            BT[n * 128 + (((s >> 3) ^ (n & 15)) << 3) + (s & 7)] = f2h(o);
        }
    }
    __syncthreads();
    const size_t blk = ((size_t)((b * 2 + h) * 32 + c)) << 14;
    const int wm = (wid >> 1) * 32, wn = (wid & 1) * 64;
    f32x4 acc[2][4];
    #pragma unroll
    for (int i = 0; i < 2; i++)
        #pragma unroll
        for (int j = 0; j < 4; j++) acc[i][j] = f32x4{0.f, 0.f, 0.f, 0.f};
    #pragma unroll
    for (int ks = 0; ks < 4; ks++) {
        f16x8 xa[2], bb[4];
        int kc = ks * 4 + quad;
        #pragma unroll
        for (int i = 0; i < 2; i++) {
            int r = wm + i * 16 + cl;
            xa[i] = *(const f16x8*)&XT[r * 128 + ((kc ^ (r & 15)) << 3)];
        }
        #pragma unroll
        for (int j = 0; j < 4; j++) {
            int r = wn + j * 16 + cl;
            bb[j] = *(const f16x8*)&BT[r * 128 + ((kc ^ (r & 15)) << 3)];
        }
        #pragma unroll
        for (int i = 0; i < 2; i++)
            #pragma unroll
            for (int j = 0; j < 4; j++)
                acc[i][j] = __builtin_amdgcn_mfma_f32_16x16x32_f16(
                    xa[i], bb[j], acc[i][j], 0, 0, 0);
    }
    u16* out = Hb + blk;
    #pragma unroll
    for (int i = 0; i < 2; i++)
        #pragma unroll
        for (int j = 0; j < 4; j++)
            #pragma unroll
            for (int r = 0; r < 4; r++)
                out[(size_t)(wm + i * 16 + quad * 4 + r) * 128 + wn + j * 16 + cl]
                    = f2h(acc[i][j][r]);
}

// ---------------------------------------------------------------------------
// Inter-chunk combine — register-prefetch. Grid (32,2,4), 256 thr.
// ---------------------------------------------------------------------------
__global__ __launch_bounds__(256) void statecombine_kernel(
    const float* __restrict__ Sb, const u16* __restrict__ Hb,
    u16* __restrict__ Hbf)
{
    __shared__ float sdec[32];
    const int h = blockIdx.y, b = blockIdx.z;
    const int e2 = blockIdx.x * 256 + threadIdx.x;
    if (threadIdx.x < 32)
        sdec[threadIdx.x] =
            __expf(Sb[(size_t)(b * LSEQ + threadIdx.x * 128 + 127) * 2 + h]);
    const size_t base2 = ((size_t)((b * 2 + h) * 32)) << 13;
    const unsigned int* src = (const unsigned int*)Hb;
    unsigned int* dst = (unsigned int*)Hbf;
    unsigned int v[32];
    #pragma unroll
    for (int c = 0; c < 32; c++)
        v[c] = src[base2 + ((size_t)c << 13) + e2];
    __syncthreads();
    float s0 = 0.f, s1 = 0.f;
    #pragma unroll
    for (int c = 0; c < 32; c++) {
        union { u16 u[2]; unsigned int q; } pk;
        pk.u[0] = f2h(s0); pk.u[1] = f2h(s1);
        dst[base2 + ((size_t)c << 13) + e2] = pk.q;
        float d = sdec[c];
        s0 = d * s0 + h2f((u16)(v[c] & 0xffffu));
        s1 = d * s1 + h2f((u16)(v[c] >> 16));
    }
}

// ---------------------------------------------------------------------------
// Per-head fused SSD. Hin fragments prefetched into VGPRs at start.
// Grid (32,2,4), 512 thr, ~145 KB LDS.
// ---------------------------------------------------------------------------
__global__ __launch_bounds__(512) void ssd_ph_kernel(
    const u16* __restrict__ zx16, const u16* __restrict__ Hbf,
    const float* __restrict__ dtb, const float* __restrict__ Sb,
    const float* __restrict__ cw, const float* __restrict__ cb,
    const float* __restrict__ Dp, u16* __restrict__ g16)
{
    __shared__ u16 raw[2560 * 8];     // staging -> G
    __shared__ u16 XT[128 * 128];
    __shared__ u16 Btok[128 * 128];
    __shared__ u16 Ctok[128 * 128];
    __shared__ float sS[128], sdt[128];
    __shared__ float scw[3][128][4];
    __shared__ float scb[3][128];
    const int c = blockIdx.x, h = blockIdx.y, b = blockIdx.z;
    const int tid = threadIdx.x, wid = tid >> 6, lane = tid & 63;
    const int quad = lane >> 4, cl = lane & 15;
    const int tok0 = b * LSEQ + c * 128;
    const size_t blk = ((size_t)((b * 2 + h) * 32 + c)) << 14;
    const int wm = (wid >> 1) * 32, wn = (wid & 1) * 64;
    // ---- prefetch Hin B-operand fragments into registers (latency hidden
    //      behind the three conv phases)
    f16x8 hinreg[4][4];
    #pragma unroll
    for (int ks = 0; ks < 4; ks++)
        #pragma unroll
        for (int j = 0; j < 4; j++) {
            int r = wn + j * 16 + cl;
            int kc = ks * 4 + quad;
            hinreg[ks][j] = *(const f16x8*)&Hbf[blk + (size_t)r * 128 + kc * 8];
        }
    for (int idx = tid; idx < 384; idx += 512) {
        int grp = idx >> 7, j = idx & 127;
        int ch = (grp == 0) ? (128 * h + j) : (grp == 1 ? 256 + j : 384 + j);
        float4 w4 = *(const float4*)&cw[ch * 4];
        scw[grp][j][0] = w4.x; scw[grp][j][1] = w4.y;
        scw[grp][j][2] = w4.z; scw[grp][j][3] = w4.w;
        scb[grp][j] = cb[ch];
    }
    if (tid < 128) {
        sS[tid] = Sb[(size_t)(tok0 + tid) * 2 + h];
        sdt[tid] = dtb[(size_t)(tok0 + tid) * 2 + h];
    }
    // ---- conv X -> XT
    #pragma unroll
    for (int i = 0; i < 5; i++) {
        int ck = i * 512 + tid;
        int r = ck >> 4; if (r > 130) r = 130;
        int cc = ck & 15;
        int tok = tok0 - 3 + r; if (tok < 0) tok = 0;
        async_lds16(zx16 + (size_t)tok * 768 + 256 + 128 * h + ((cc ^ (r & 15)) << 3),
                    (void*)(raw + (i * 512 + (tid & ~63)) * 8));
    }
    __syncthreads();
    if (c == 0 && tid < 48) *(uint4*)&raw[tid * 8] = make_uint4(0, 0, 0, 0);
    __syncthreads();
    #pragma unroll
    for (int it = 0; it < 4; it++) {
        int idx = it * 512 + tid;
        int s = idx & 127, pg = idx >> 7;
        f16x8 v[4];
        #pragma unroll
        for (int k = 0; k < 4; k++) {
            int rr = s + k;
            v[k] = *(const f16x8*)&raw[rr * 128 + ((pg ^ (rr & 15)) << 3)];
        }
        #pragma unroll
        for (int j = 0; j < 8; j++) {
            int p = pg * 8 + j;
            float o = scb[0][p] + (float)v[0][j] * scw[0][p][0]
                    + (float)v[1][j] * scw[0][p][1]
                    + (float)v[2][j] * scw[0][p][2]
                    + (float)v[3][j] * scw[0][p][3];
            XT[p * 128 + (((s >> 3) ^ (p & 15)) << 3) + (s & 7)] = f2h(silu_f(o));
        }
    }
    __syncthreads();
    // ---- conv B -> Btok (token-major)
    #pragma unroll
    for (int i = 0; i < 5; i++) {
        int ck = i * 512 + tid;
        int r = ck >> 4; if (r > 130) r = 130;
        int cc = ck & 15;
        int tok = tok0 - 3 + r; if (tok < 0) tok = 0;
        async_lds16(zx16 + (size_t)tok * 768 + 512 + ((cc ^ (r & 15)) << 3),
                    (void*)(raw + (i * 512 + (tid & ~63)) * 8));
    }
    __syncthreads();
    if (c == 0 && tid < 48) *(uint4*)&raw[tid * 8] = make_uint4(0, 0, 0, 0);
    __syncthreads();
    #pragma unroll
    for (int it = 0; it < 4; it++) {
        int idx = it * 512 + tid;
        int t = idx & 127, ng = idx >> 7;
        f16x8 v[4];
        #pragma unroll
        for (int k = 0; k < 4; k++) {
            int rr = t + k;
            v[k] = *(const f16x8*)&raw[rr * 128 + ((ng ^ (rr & 15)) << 3)];
        }
        union { u16 u[8]; uint4 q; } pk;
        #pragma unroll
        for (int j = 0; j < 8; j++) {
            int n = ng * 8 + j;
            float o = scb[1][n] + (float)v[0][j] * scw[1][n][0]
                    + (float)v[1][j] * scw[1][n][1]
                    + (float)v[2][j] * scw[1][n][2]
                    + (float)v[3][j] * scw[1][n][3];
            pk.u[j] = f2h(silu_f(o));
        }
        *(uint4*)&Btok[t * 128 + ((ng ^ (t & 15)) << 3)] = pk.q;
    }
    __syncthreads();
    // ---- conv C -> Ctok (token-major)
    #pragma unroll
    for (int i = 0; i < 5; i++) {
        int ck = i * 512 + tid;
        int r = ck >> 4; if (r > 130) r = 130;
        int cc = ck & 15;
        int tok = tok0 - 3 + r; if (tok < 0) tok = 0;
        async_lds16(zx16 + (size_t)tok * 768 + 640 + ((cc ^ (r & 15)) << 3),
                    (void*)(raw + (i * 512 + (tid & ~63)) * 8));
    }
    __syncthreads();
    if (c == 0 && tid < 48) *(uint4*)&raw[tid * 8] = make_uint4(0, 0, 0, 0);
    __syncthreads();
    #pragma unroll
    for (int it = 0; it < 4; it++) {
        int idx = it * 512 + tid;
        int t = idx & 127, ng = idx >> 7;
        f16x8 v[4];
        #pragma unroll
        for (int k = 0; k < 4; k++) {
            int rr = t + k;
            v[k] = *(const f16x8*)&raw[rr * 128 + ((ng ^ (rr & 15)) << 3)];
        }
        union { u16 u[8]; uint4 q; } pk;
        #pragma unroll
        for (int j = 0; j < 8; j++) {
            int n = ng * 8 + j;
            float o = scb[2][n] + (float)v[0][j] * scw[2][n][0]
                    + (float)v[1][j] * scw[2][n][1]
                    + (float)v[2][j] * scw[2][n][2]
                    + (float)v[3][j] * scw[2][n][3];
            pk.u[j] = f2h(silu_f(o));
        }
        *(uint4*)&Ctok[t * 128 + ((ng ^ (t & 15)) << 3)] = pk.q;
    }
    __syncthreads();   // Ctok ready; raw's last readers (conv C) done
    // ---- phase 1: Y = C @ Hin^T (Hin from registers); scale by exp(S_t)
    f32x4 acc[2][4];
    #pragma unroll
    for (int i = 0; i < 2; i++)
        #pragma unroll
        for (int j = 0; j < 4; j++) acc[i][j] = f32x4{0.f, 0.f, 0.f, 0.f};
    #pragma unroll
    for (int ks = 0; ks < 4; ks++) {
        f16x8 ca[2];
        int kc = ks * 4 + quad;
        #pragma unroll
        for (int i = 0; i < 2; i++) {
            int r = wm + i * 16 + cl;
            ca[i] = *(const f16x8*)&Ctok[r * 128 + ((kc ^ (r & 15)) << 3)];
        }
        #pragma unroll
        for (int i = 0; i < 2; i++)
            #pragma unroll
            for (int j = 0; j < 4; j++)
                acc[i][j] = __builtin_amdgcn_mfma_f32_16x16x32_f16(
                    ca[i], hinreg[ks][j], acc[i][j], 0, 0, 0);
    }
    #pragma unroll
    for (int i = 0; i < 2; i++)
        #pragma unroll
        for (int r = 0; r < 4; r++) {
            float e = __expf(sS[wm + i * 16 + quad * 4 + r]);
            #pragma unroll
            for (int j = 0; j < 4; j++) acc[i][j][r] *= e;
        }
    // ---- phase 2: S = C @ B^T (triangular skip)
    f32x4 sacc[2][4];
    #pragma unroll
    for (int i = 0; i < 2; i++)
        #pragma unroll
        for (int j = 0; j < 4; j++) sacc[i][j] = f32x4{0.f, 0.f, 0.f, 0.f};
    #pragma unroll
    for (int ks = 0; ks < 4; ks++) {
        f16x8 cs[2], bs[4];
        int kc = ks * 4 + quad;
        #pragma unroll
        for (int i2 = 0; i2 < 2; i2++) {
            int r = wm + i2 * 16 + cl;
            cs[i2] = *(const f16x8*)&Ctok[r * 128 + ((kc ^ (r & 15)) << 3)];
        }
        #pragma unroll
        for (int j = 0; j < 4; j++) {
            int r = wn + j * 16 + cl;
            bs[j] = *(const f16x8*)&Btok[r * 128 + ((kc ^ (r & 15)) << 3)];
        }
        #pragma unroll
        for (int i2 = 0; i2 < 2; i2++)
            #pragma unroll
            for (int j = 0; j < 4; j++)
                if (wm + i2 * 16 + 15 >= wn + j * 16)
                    sacc[i2][j] = __builtin_amdgcn_mfma_f32_16x16x32_f16(
                        cs[i2], bs[j], sacc[i2][j], 0, 0, 0);
    }
    // ---- G = mask ∘ S ∘ exp(St-Ss) ∘ dt_s -> raw (disjoint per wave)
    #pragma unroll
    for (int i2 = 0; i2 < 2; i2++)
        #pragma unroll
        for (int r = 0; r < 4; r++) {
            int t = wm + i2 * 16 + quad * 4 + r;
            float Stv = sS[t];
            #pragma unroll
            for (int j = 0; j < 4; j++) {
                int s = wn + j * 16 + cl;
                float gv = 0.f;
                if (s <= t) gv = sacc[i2][j][r] * __expf(Stv - sS[s]) * sdt[s];
                raw[t * 128 + (((s >> 3) ^ (t & 15)) << 3) + (s & 7)] = f2h(gv);
            }
        }
    __syncthreads();
    // ---- phase 3: Y += G @ X
    #pragma unroll
    for (int ks = 0; ks < 4; ks++) {
        f16x8 ga[2], xb[4];
        int kc = ks * 4 + quad;
        #pragma unroll
        for (int i = 0; i < 2; i++) {
            int r = wm + i * 16 + cl;
            ga[i] = *(const f16x8*)&raw[r * 128 + ((kc ^ (r & 15)) << 3)];
        }
        #pragma unroll
        for (int j = 0; j < 4; j++) {
            int r = wn + j * 16 + cl;
            xb[j] = *(const f16x8*)&XT[r * 128 + ((kc ^ (r & 15)) << 3)];
        }
        #pragma unroll
        for (int i = 0; i < 2; i++)
            #pragma unroll
            for (int j = 0; j < 4; j++)
                acc[i][j] = __builtin_amdgcn_mfma_f32_16x16x32_f16(
                    ga[i], xb[j], acc[i][j], 0, 0, 0);
    }
    // ---- epilogue: g = (Y + D*x)*silu(z)
    const float dco = Dp[h];
    #pragma unroll
    for (int i = 0; i < 2; i++)
        #pragma unroll
        for (int r = 0; r < 4; r++) {
            int t = wm + i * 16 + quad * 4 + r;
            u16* row = g16 + (size_t)(tok0 + t) * 256 + h * 128;
            #pragma unroll
            for (int j = 0; j < 4; j++) {
                int p = wn + j * 16 + cl;
                float xv = h2f(XT[p * 128 + (((t >> 3) ^ (p & 15)) << 3) + (t & 7)]);
                float zv = h2f(zx16[(size_t)(tok0 + t) * 768 + h * 128 + p]);
                row[p] = f2h((acc[i][j][r] + dco * xv) * silu_f(zv));
            }
        }
}

// ---------------------------------------------------------------------------
// out-proj GEMM (K=256, N=128, BM=64): rstd from staged sA tiles (no extra
// global pass), gnw folded into W cvt, + residual + RMS (+ fused final proj).
// ---------------------------------------------------------------------------
__global__ __launch_bounds__(256) void gemm_outrms_kernel(
    const u16* __restrict__ A, const float* __restrict__ Wf,
    const float* __restrict__ gnw, const float* __restrict__ rmsw,
    u16* __restrict__ xp16, u16* __restrict__ hbuf16, u16* __restrict__ hn16,
    const float* __restrict__ out_wf, const float* __restrict__ out_b,
    float* __restrict__ dout, int mode)
{
    __shared__ u16 sA[64 * 64];
    __shared__ u16 sW[128 * 64];
    __shared__ float red[64][33];
    __shared__ float srstd[64];
    __shared__ float redp[64][5];
    __shared__ float rstdg[64];
    __shared__ u16 hn2[64 * 128];
    __shared__ u16 ow[64 * 128];
    const int K = 256;
    const int m0 = blockIdx.y * 64;
    const int tid = threadIdx.x, wid = tid >> 6, lane = tid & 63;
    const int wm = (wid >> 1) * 32, wn = (wid & 1) * 64;
    const int quad = lane >> 4, cl = lane & 15;
    f32x4 acc[2][4];
    #pragma unroll
    for (int i = 0; i < 2; i++)
        #pragma unroll
        for (int j = 0; j < 4; j++) acc[i][j] = f32x4{0.f, 0.f, 0.f, 0.f};

    float ssq = 0.f;   // per-thread partial sum-of-squares of g (row tid>>2)
    for (int k0 = 0; k0 < K; k0 += 64) {
        #pragma unroll
        for (int i = 0; i < 2; i++) {
            int ck = i * 256 + tid;
            int r = ck >> 3, cc = ck & 7;
            int csw = (cc ^ (r & 7)) << 3;
            async_lds16(A + (size_t)(m0 + r) * K + k0 + csw,
                        (void*)(sA + (i * 256 + (tid & ~63)) * 8));
        }
        #pragma unroll
        for (int i = 0; i < 4; i++) {
            int ck = i * 256 + tid;
            int r = ck >> 3, cc = ck & 7;
            int csw = (cc ^ (r & 7)) << 3;
            *(uint4*)&sW[ck * 8] = cvt8g(Wf + (size_t)r * K + k0 + csw,
                                         gnw + k0 + csw);
        }
        __syncthreads();
        {   // accumulate squares from staged A (swizzle permutes within row)
            int rr = tid >> 2, q = tid & 3;
            f16x8 v0 = *(const f16x8*)&sA[rr * 64 + q * 16];
            f16x8 v1 = *(const f16x8*)&sA[rr * 64 + q * 16 + 8];
            #pragma unroll
            for (int j = 0; j < 8; j++) {
                float a = (float)v0[j], bq = (float)v1[j];
                ssq += a * a + bq * bq;
            }
        }
        #pragma unroll
        for (int ks = 0; ks < 2; ks++) {
            f16x8 af[2], wv[4];
            int kc = ks * 4 + quad;
            #pragma unroll
            for (int i = 0; i < 2; i++) {
                int r = wm + i * 16 + cl;
                af[i] = *(const f16x8*)&sA[r * 64 + ((kc ^ (r & 7)) << 3)];
            }
            #pragma unroll
            for (int j = 0; j < 4; j++) {
                int r = wn + j * 16 + cl;
                wv[j] = *(const f16x8*)&sW[r * 64 + ((kc ^ (r & 7)) << 3)];
            }
            #pragma unroll
            for (int i = 0; i < 2; i++)
                #pragma unroll
                for (int j = 0; j < 4; j++)
                    acc[i][j] = __builtin_amdgcn_mfma_f32_16x16x32_f16(
                        af[i], wv[j], acc[i][j], 0, 0, 0);
        }
        __syncthreads();
    }
    redp[tid >> 2][tid & 3] = ssq;
    __syncthreads();
    if (tid < 64)
        rstdg[tid] = rsqrtf((redp[tid][0] + redp[tid][1] + redp[tid][2]
                             + redp[tid][3]) * (1.f / 256.f) + 1e-5f);
    __syncthreads();
    const int slot = (wid & 1) * 16 + cl;
    #pragma unroll
    for (int i = 0; i < 2; i++)
        #pragma unroll
        for (int r = 0; r < 4; r++) {
            int t = wm + i * 16 + quad * 4 + r;
            size_t ob = (size_t)(m0 + t) * 128;
            float rg = rstdg[t];
            float ssp = 0.f;
            #pragma unroll
            for (int j = 0; j < 4; j++) {
                int n = wn + j * 16 + cl;
                float v = acc[i][j][r] * rg + h2f(hbuf16[ob + n]);
                acc[i][j][r] = v;
                ssp += v * v;
            }
            red[t][slot] = ssp;
        }
    __syncthreads();
    if (tid < 64) {
        float s = 0.f;
        #pragma unroll
        for (int sl = 0; sl < 32; sl++) s += red[tid][sl];
        srstd[tid] = rsqrtf(s * (1.f / 128.f) + 1e-5f);
    }
    __syncthreads();
    #pragma unroll
    for (int i = 0; i < 2; i++)
        #pragma unroll
        for (int r = 0; r < 4; r++) {
            int t = wm + i * 16 + quad * 4 + r;
            size_t ob = (size_t)(m0 + t) * 128;
            float rstd = srstd[t];
            #pragma unroll
            for (int j = 0; j < 4; j++) {
                int n = wn + j * 16 + cl;
                float v = acc[i][j][r];
                float val = v * rstd * rmsw[n];
                if (mode == 1) {
                    hbuf16[ob + n] = f2h(v);
                    hn16[ob + n] = f2h(val);
                } else {
                    val += h2f(xp16[ob + n]);
                    hn2[t * 128 + (((n >> 3) ^ (t & 15)) << 3) + (n & 7)] = f2h(val);
                }
            }
        }
    if (mode == 1) return;
    #pragma unroll
    for (int i = 0; i < 4; i++) {
        int ck = i * 256 + tid;
        int rr = ck >> 4, cc = ck & 15;
        int csw = (cc ^ (rr & 15)) << 3;
        *(uint4*)&ow[ck * 8] = cvt8(out_wf + (size_t)rr * 128 + csw);
    }
    __syncthreads();
    const int wm4 = (wid >> 1) * 32, wn4 = (wid & 1) * 32;
    f32x4 acc2[2][2];
    #pragma unroll
    for (int i = 0; i < 2; i++)
        #pragma unroll
        for (int j = 0; j < 2; j++) acc2[i][j] = f32x4{0.f, 0.f, 0.f, 0.f};
    #pragma unroll
    for (int ks = 0; ks < 4; ks++) {
        f16x8 af2[2], wf2[2];
        int kc = ks * 4 + quad;
        #pragma unroll
        for (int i = 0; i < 2; i++) {
            int r = wm4 + i * 16 + cl;
            af2[i] = *(const f16x8*)&hn2[r * 128 + ((kc ^ (r & 15)) << 3)];
        }
        #pragma unroll
        for (int j = 0; j < 2; j++) {
            int rr = wn4 + j * 16 + cl;
            wf2[j] = *(const f16x8*)&ow[rr * 128 + ((kc ^ (rr & 15)) << 3)];
        }
        #pragma unroll
        for (int i = 0; i < 2; i++)
            #pragma unroll
            for (int j = 0; j < 2; j++)
                acc2[i][j] = __builtin_amdgcn_mfma_f32_16x16x32_f16(
                    af2[i], wf2[j], acc2[i][j], 0, 0, 0);
    }
    #pragma unroll
    for (int i = 0; i < 2; i++) {
        int m = m0 + wm4 + i * 16 + quad * 4;
        #pragma unroll
        for (int j = 0; j < 2; j++) {
            int n = wn4 + j * 16 + cl;
            float bv = out_b[n];
            #pragma unroll
            for (int r = 0; r < 4; r++)
                dout[(size_t)(m + r) * 64 + n] = acc2[i][j][r] + bv;
        }
    }
}

// ---------------------------------------------------------------------------
extern "C" void kernel_launch(void* const* d_in, const int* in_sizes, int n_in,
                              void* d_out, int out_size, void* d_ws, size_t ws_size,
                              hipStream_t stream)
{
    (void)in_sizes; (void)n_in; (void)out_size; (void)ws_size;
    const float* x       = (const float*)d_in[0];
    const float* in_w    = (const float*)d_in[1];
    const float* in_b    = (const float*)d_in[2];
    const float* out_w   = (const float*)d_in[3];
    const float* out_b   = (const float*)d_in[4];
    const float* l_rms_w = (const float*)d_in[5];
    const float* l_in_w  = (const float*)d_in[6];
    const float* conv_w  = (const float*)d_in[7];
    const float* conv_b  = (const float*)d_in[8];
    const float* dt_bias = (const float*)d_in[9];
    const float* A_log   = (const float*)d_in[10];
    const float* D_p     = (const float*)d_in[11];
    const float* gnorm_w = (const float*)d_in[12];
    const float* l_out_w = (const float*)d_in[13];
    const float* fnorm_w = (const float*)d_in[14];

    char* w = (char*)d_ws;
    u16*   xp16   = (u16*)(w);                  // 4.19 MB
    u16*   hbuf16 = (u16*)(w + 4194304);        // 4.19 MB
    u16*   hn16   = (u16*)(w + 8388608);        // 4.19 MB
    u16*   zx16   = (u16*)(w + 12582912);       // 25.17 MB
    float* dtb    = (float*)(w + 37748736);     // 131 KB
    float* Sb     = (float*)(w + 37879808);     // 131 KB
    u16*   Hb     = (u16*)(w + 38010880);       // 8.39 MB
    u16*   Hbf    = (u16*)(w + 46399488);       // 8.39 MB
    u16*   g16    = (u16*)(w + 54788096);       // 8.39 MB

    gemm_rms0_kernel<<<dim3(1, 256), 256, 0, stream>>>(
        x, in_w, in_b, l_rms_w, xp16, hbuf16, hn16);

    for (int i = 0; i < 2; i++) {
        gemm_inproj_kernel<<<dim3(6, 128), 256, 0, stream>>>(
            hn16, l_in_w + (size_t)i * 770 * 128, zx16, dtb, Sb,
            dt_bias + i * 2, A_log + i * 2);
        chunkstate_conv_kernel<<<dim3(32, 2, 4), 512, 0, stream>>>(
            zx16, conv_w + i * 2048, conv_b + i * 512, dtb, Sb, Hb);
        statecombine_kernel<<<dim3(32, 2, 4), 256, 0, stream>>>(Sb, Hb, Hbf);
        ssd_ph_kernel<<<dim3(32, 2, 4), 512, 0, stream>>>(
            zx16, Hbf, dtb, Sb, conv_w + i * 2048, conv_b + i * 512,
            D_p + i * 2, g16);
        gemm_outrms_kernel<<<dim3(1, 256), 256, 0, stream>>>(
            g16, l_out_w + (size_t)i * 128 * 256, gnorm_w + i * 256,
            (i == 0) ? (l_rms_w + 128) : fnorm_w, xp16, hbuf16, hn16,
            out_w, out_b, (float*)d_out, (i == 0) ? 1 : 3);
    }
}

// Round 13
// 226.903 us; speedup vs baseline: 1.0730x; 1.0730x over previous
//
#include <hip/hip_runtime.h>
#include <cstddef>
#include <cstdint>

// MambaDoc — round 13: exact R11 structure (226.9 µs verified) + ONE change:
// outrms folds the rstd sum-of-squares into the GEMM's staged-A tiles
// (deletes the 8.4 MB prologue re-read + one barrier). R12's other two
// changes (inproj tail block, ssd_ph register prefetch) reverted.

#define LSEQ 4096
#define MTOK 16384

typedef unsigned short u16;
typedef _Float16 f16x8 __attribute__((ext_vector_type(8)));
typedef float f32x4 __attribute__((ext_vector_type(4)));

__device__ __forceinline__ u16 f2h(float x) {
    return __builtin_bit_cast(u16, (_Float16)x);
}
__device__ __forceinline__ float h2f(u16 u) {
    return (float)__builtin_bit_cast(_Float16, u);
}
__device__ __forceinline__ float silu_f(float x) { return x / (1.f + __expf(-x)); }

__device__ __forceinline__ void async_lds16(const void* g, void* l) {
    __builtin_amdgcn_global_load_lds(
        (const __attribute__((address_space(1))) unsigned int*)g,
        (__attribute__((address_space(3))) unsigned int*)l, 16, 0, 0);
}

__device__ __forceinline__ uint4 cvt8(const float* __restrict__ src) {
    float4 a = *(const float4*)src;
    float4 b = *(const float4*)(src + 4);
    union { u16 u[8]; uint4 q; } pk;
    pk.u[0] = f2h(a.x); pk.u[1] = f2h(a.y); pk.u[2] = f2h(a.z); pk.u[3] = f2h(a.w);
    pk.u[4] = f2h(b.x); pk.u[5] = f2h(b.y); pk.u[6] = f2h(b.z); pk.u[7] = f2h(b.w);
    return pk.q;
}

__device__ __forceinline__ uint4 cvt8g(const float* __restrict__ src,
                                       const float* __restrict__ gw) {
    float4 a = *(const float4*)src;
    float4 b = *(const float4*)(src + 4);
    float4 ga = *(const float4*)gw;
    float4 gb = *(const float4*)(gw + 4);
    union { u16 u[8]; uint4 q; } pk;
    pk.u[0] = f2h(a.x * ga.x); pk.u[1] = f2h(a.y * ga.y);
    pk.u[2] = f2h(a.z * ga.z); pk.u[3] = f2h(a.w * ga.w);
    pk.u[4] = f2h(b.x * gb.x); pk.u[5] = f2h(b.y * gb.y);
    pk.u[6] = f2h(b.z * gb.z); pk.u[7] = f2h(b.w * gb.w);
    return pk.q;
}

// ---------------------------------------------------------------------------
// Initial projection + fused RMSNorm. BM=64, grid (1,256).
// ---------------------------------------------------------------------------
__global__ __launch_bounds__(256) void gemm_rms0_kernel(
    const float* __restrict__ xf, const float* __restrict__ wf,
    const float* __restrict__ bias, const float* __restrict__ rmsw,
    u16* __restrict__ xp16, u16* __restrict__ hbuf16, u16* __restrict__ hn16)
{
    __shared__ u16 sA[64 * 64];
    __shared__ u16 sW[128 * 64];
    __shared__ float red[64][33];
    __shared__ float srstd[64];
    const int m0 = blockIdx.y * 64;
    const int tid = threadIdx.x, wid = tid >> 6, lane = tid & 63;
    const int wm = (wid >> 1) * 32, wn = (wid & 1) * 64;
    const int quad = lane >> 4, cl = lane & 15;
    #pragma unroll
    for (int i = 0; i < 2; i++) {
        int ck = i * 256 + tid;
        int r = ck >> 3, cc = ck & 7;
        int csw = (cc ^ (r & 7)) << 3;
        *(uint4*)&sA[ck * 8] = cvt8(xf + (size_t)(m0 + r) * 64 + csw);
    }
    #pragma unroll
    for (int i = 0; i < 4; i++) {
        int ck = i * 256 + tid;
        int r = ck >> 3, cc = ck & 7;
        int csw = (cc ^ (r & 7)) << 3;
        *(uint4*)&sW[ck * 8] = cvt8(wf + (size_t)r * 64 + csw);
    }
    __syncthreads();
    f32x4 acc[2][4];
    #pragma unroll
    for (int i = 0; i < 2; i++)
        #pragma unroll
        for (int j = 0; j < 4; j++) acc[i][j] = f32x4{0.f, 0.f, 0.f, 0.f};
    #pragma unroll
    for (int ks = 0; ks < 2; ks++) {
        f16x8 af[2], wv[4];
        int kc = ks * 4 + quad;
        #pragma unroll
        for (int i = 0; i < 2; i++) {
            int r = wm + i * 16 + cl;
            af[i] = *(const f16x8*)&sA[r * 64 + ((kc ^ (r & 7)) << 3)];
        }
        #pragma unroll
        for (int j = 0; j < 4; j++) {
            int r = wn + j * 16 + cl;
            wv[j] = *(const f16x8*)&sW[r * 64 + ((kc ^ (r & 7)) << 3)];
        }
        #pragma unroll
        for (int i = 0; i < 2; i++)
            #pragma unroll
            for (int j = 0; j < 4; j++)
                acc[i][j] = __builtin_amdgcn_mfma_f32_16x16x32_f16(
                    af[i], wv[j], acc[i][j], 0, 0, 0);
    }
    const int slot = (wid & 1) * 16 + cl;
    #pragma unroll
    for (int i = 0; i < 2; i++)
        #pragma unroll
        for (int r = 0; r < 4; r++) {
            int t = wm + i * 16 + quad * 4 + r;
            float ssp = 0.f;
            #pragma unroll
            for (int j = 0; j < 4; j++) {
                int n = wn + j * 16 + cl;
                float v = acc[i][j][r] + bias[n];
                acc[i][j][r] = v;
                ssp += v * v;
            }
            red[t][slot] = ssp;
        }
    __syncthreads();
    if (tid < 64) {
        float s = 0.f;
        #pragma unroll
        for (int sl = 0; sl < 32; sl++) s += red[tid][sl];
        srstd[tid] = rsqrtf(s * (1.f / 128.f) + 1e-5f);
    }
    __syncthreads();
    #pragma unroll
    for (int i = 0; i < 2; i++)
        #pragma unroll
        for (int r = 0; r < 4; r++) {
            int t = wm + i * 16 + quad * 4 + r;
            size_t ob = (size_t)(m0 + t) * 128;
            float rstd = srstd[t];
            #pragma unroll
            for (int j = 0; j < 4; j++) {
                int n = wn + j * 16 + cl;
                float v = acc[i][j][r];
                u16 vh = f2h(v);
                xp16[ob + n] = vh;
                hbuf16[ob + n] = vh;
                hn16[ob + n] = f2h(v * rstd * rmsw[n]);
            }
        }
}

// ---------------------------------------------------------------------------
// in_proj GEMM fp16 (K=128). Grid (7, 128). (R11 version)
// ---------------------------------------------------------------------------
__global__ __launch_bounds__(256) void gemm_inproj_kernel(
    const u16* __restrict__ A, const float* __restrict__ Wf,
    u16* __restrict__ zx16, float* __restrict__ dtb, float* __restrict__ Sb,
    const float* __restrict__ dt_bias, const float* __restrict__ A_log)
{
    __shared__ u16 sA[128 * 64];
    __shared__ u16 sW[128 * 64];
    __shared__ float sdt[2][128];
    const int K = 128, N = 770;
    const int n0 = blockIdx.x * 128, m0 = blockIdx.y * 128;
    const int tid = threadIdx.x, wid = tid >> 6, lane = tid & 63;
    const int wm = (wid >> 1) * 64, wn = (wid & 1) * 64;
    const int quad = lane >> 4, cl = lane & 15;
    f32x4 acc[4][4];
    #pragma unroll
    for (int i = 0; i < 4; i++)
        #pragma unroll
        for (int j = 0; j < 4; j++) acc[i][j] = f32x4{0.f, 0.f, 0.f, 0.f};

    for (int k0 = 0; k0 < K; k0 += 64) {
        #pragma unroll
        for (int i = 0; i < 4; i++) {
            int ck = i * 256 + tid;
            int r = ck >> 3, cc = ck & 7;
            int csw = (cc ^ (r & 7)) << 3;
            async_lds16(A + (size_t)(m0 + r) * K + k0 + csw,
                        (void*)(sA + (i * 256 + (tid & ~63)) * 8));
        }
        #pragma unroll
        for (int i = 0; i < 4; i++) {
            int ck = i * 256 + tid;
            int r = ck >> 3, cc = ck & 7;
            int csw = (cc ^ (r & 7)) << 3;
            int rr = n0 + r; if (rr >= N) rr = N - 1;
            *(uint4*)&sW[ck * 8] = cvt8(Wf + (size_t)rr * K + k0 + csw);
        }
        __syncthreads();
        #pragma unroll
        for (int ks = 0; ks < 2; ks++) {
            f16x8 af[4], wv[4];
            int kc = ks * 4 + quad;
            #pragma unroll
            for (int i = 0; i < 4; i++) {
                int r = wm + i * 16 + cl;
                af[i] = *(const f16x8*)&sA[r * 64 + ((kc ^ (r & 7)) << 3)];
            }
            #pragma unroll
            for (int j = 0; j < 4; j++) {
                int r = wn + j * 16 + cl;
                wv[j] = *(const f16x8*)&sW[r * 64 + ((kc ^ (r & 7)) << 3)];
            }
            #pragma unroll
            for (int i = 0; i < 4; i++)
                #pragma unroll
                for (int j = 0; j < 4; j++)
                    acc[i][j] = __builtin_amdgcn_mfma_f32_16x16x32_f16(
                        af[i], wv[j], acc[i][j], 0, 0, 0);
        }
        __syncthreads();
    }
    if (blockIdx.x < 6) {
        #pragma unroll
        for (int i = 0; i < 4; i++) {
            int m = m0 + wm + i * 16 + quad * 4;
            #pragma unroll
            for (int j = 0; j < 4; j++) {
                int n = n0 + wn + j * 16 + cl;
                #pragma unroll
                for (int r = 0; r < 4; r++)
                    zx16[(size_t)(m + r) * 768 + n] = f2h(acc[i][j][r]);
            }
        }
    } else {
        if ((wid & 1) == 0 && cl < 2) {
            #pragma unroll
            for (int i = 0; i < 4; i++)
                #pragma unroll
                for (int r = 0; r < 4; r++)
                    sdt[cl][wm + i * 16 + quad * 4 + r] = acc[i][0][r];
        }
        __syncthreads();
        const int hh = tid >> 7, t = tid & 127;
        float raw = sdt[hh][t] + dt_bias[hh];
        float dt = fmaxf(raw, 0.f) + log1pf(__expf(-fabsf(raw)));
        dtb[(size_t)(m0 + t) * 2 + hh] = dt;
        float ad = -__expf(A_log[hh]) * dt;
        __syncthreads();
        sdt[hh][t] = ad;
        __syncthreads();
        for (int off = 1; off < 128; off <<= 1) {
            float add = (t >= off) ? sdt[hh][t - off] : 0.f;
            __syncthreads();
            sdt[hh][t] += add;
            __syncthreads();
        }
        Sb[(size_t)(m0 + t) * 2 + hh] = sdt[hh][t];
    }
}

// ---------------------------------------------------------------------------
// chunkstate + inlined conv. Grid (32,2,4), 512 thr. (R11 version)
// ---------------------------------------------------------------------------
__global__ __launch_bounds__(512) void chunkstate_conv_kernel(
    const u16* __restrict__ zx16, const float* __restrict__ cw,
    const float* __restrict__ cb, const float* __restrict__ dtb,
    const float* __restrict__ Sb, u16* __restrict__ Hb)
{
    __shared__ u16 raw[2560 * 8];
    __shared__ u16 XT[128 * 128];
    __shared__ u16 BT[128 * 128];
    __shared__ float scw[2][128][4];
    __shared__ float scb[2][128];
    __shared__ float ssw[128];
    const int c = blockIdx.x, h = blockIdx.y, b = blockIdx.z;
    const int tid = threadIdx.x, wid = tid >> 6, lane = tid & 63;
    const int quad = lane >> 4, cl = lane & 15;
    const int tok0 = b * LSEQ + c * 128;
    for (int idx = tid; idx < 256; idx += 512) {
        int grp = idx >> 7, j = idx & 127;
        int ch = grp ? (256 + j) : (128 * h + j);
        float4 w4 = *(const float4*)&cw[ch * 4];
        scw[grp][j][0] = w4.x; scw[grp][j][1] = w4.y;
        scw[grp][j][2] = w4.z; scw[grp][j][3] = w4.w;
        scb[grp][j] = cb[ch];
    }
    if (tid < 128) {
        float Sl = Sb[(size_t)(tok0 + 127) * 2 + h];
        ssw[tid] = __expf(Sl - Sb[(size_t)(tok0 + tid) * 2 + h])
                   * dtb[(size_t)(tok0 + tid) * 2 + h];
    }
    #pragma unroll
    for (int i = 0; i < 5; i++) {
        int ck = i * 512 + tid;
        int r = ck >> 4; if (r > 130) r = 130;
        int cc = ck & 15;
        int tok = tok0 - 3 + r; if (tok < 0) tok = 0;
        async_lds16(zx16 + (size_t)tok * 768 + 256 + 128 * h + ((cc ^ (r & 15)) << 3),
                    (void*)(raw + (i * 512 + (tid & ~63)) * 8));
    }
    __syncthreads();
    if (c == 0 && tid < 48) *(uint4*)&raw[tid * 8] = make_uint4(0, 0, 0, 0);
    __syncthreads();
    #pragma unroll
    for (int it = 0; it < 4; it++) {
        int idx = it * 512 + tid;
        int s = idx & 127, pg = idx >> 7;
        f16x8 v[4];
        #pragma unroll
        for (int k = 0; k < 4; k++) {
            int rr = s + k;
            v[k] = *(const f16x8*)&raw[rr * 128 + ((pg ^ (rr & 15)) << 3)];
        }
        #pragma unroll
        for (int j = 0; j < 8; j++) {
            int p = pg * 8 + j;
            float o = scb[0][p] + (float)v[0][j] * scw[0][p][0]
                    + (float)v[1][j] * scw[0][p][1]
                    + (float)v[2][j] * scw[0][p][2]
                    + (float)v[3][j] * scw[0][p][3];
            o = silu_f(o);
            XT[p * 128 + (((s >> 3) ^ (p & 15)) << 3) + (s & 7)] = f2h(o);
        }
    }
    __syncthreads();
    #pragma unroll
    for (int i = 0; i < 5; i++) {
        int ck = i * 512 + tid;
        int r = ck >> 4; if (r > 130) r = 130;
        int cc = ck & 15;
        int tok = tok0 - 3 + r; if (tok < 0) tok = 0;
        async_lds16(zx16 + (size_t)tok * 768 + 512 + ((cc ^ (r & 15)) << 3),
                    (void*)(raw + (i * 512 + (tid & ~63)) * 8));
    }
    __syncthreads();
    if (c == 0 && tid < 48) *(uint4*)&raw[tid * 8] = make_uint4(0, 0, 0, 0);
    __syncthreads();
    #pragma unroll
    for (int it = 0; it < 4; it++) {
        int idx = it * 512 + tid;
        int s = idx & 127, ng = idx >> 7;
        f16x8 v[4];
        #pragma unroll
        for (int k = 0; k < 4; k++) {
            int rr = s + k;
            v[k] = *(const f16x8*)&raw[rr * 128 + ((ng ^ (rr & 15)) << 3)];
        }
        float wsv = ssw[s];
        #pragma unroll
        for (int j = 0; j < 8; j++) {
            int n = ng * 8 + j;
            float o = scb[1][n] + (float)v[0][j] * scw[1][n][0]
                    + (float)v[1][j] * scw[1][n][1]
                    + (float)v[2][j] * scw[1][n][2]
                    + (float)v[3][j] * scw[1][n][3];
            o = silu_f(o) * wsv;
            BT[n * 128 + (((s >> 3) ^ (n & 15)) << 3) + (s & 7)] = f2h(o);
        }
    }
    __syncthreads();
    const size_t blk = ((size_t)((b * 2 + h) * 32 + c)) << 14;
    const int wm = (wid >> 1) * 32, wn = (wid & 1) * 64;
    f32x4 acc[2][4];
    #pragma unroll
    for (int i = 0; i < 2; i++)
        #pragma unroll
        for (int j = 0; j < 4; j++) acc[i][j] = f32x4{0.f, 0.f, 0.f, 0.f};
    #pragma unroll
    for (int ks = 0; ks < 4; ks++) {
        f16x8 xa[2], bb[4];
        int kc = ks * 4 + quad;
        #pragma unroll
        for (int i = 0; i < 2; i++) {
            int r = wm + i * 16 + cl;
            xa[i] = *(const f16x8*)&XT[r * 128 + ((kc ^ (r & 15)) << 3)];
        }
        #pragma unroll
        for (int j = 0; j < 4; j++) {
            int r = wn + j * 16 + cl;
            bb[j] = *(const f16x8*)&BT[r * 128 + ((kc ^ (r & 15)) << 3)];
        }
        #pragma unroll
        for (int i = 0; i < 2; i++)
            #pragma unroll
            for (int j = 0; j < 4; j++)
                acc[i][j] = __builtin_amdgcn_mfma_f32_16x16x32_f16(
                    xa[i], bb[j], acc[i][j], 0, 0, 0);
    }
    u16* out = Hb + blk;
    #pragma unroll
    for (int i = 0; i < 2; i++)
        #pragma unroll
        for (int j = 0; j < 4; j++)
            #pragma unroll
            for (int r = 0; r < 4; r++)
                out[(size_t)(wm + i * 16 + quad * 4 + r) * 128 + wn + j * 16 + cl]
                    = f2h(acc[i][j][r]);
}

// ---------------------------------------------------------------------------
// Inter-chunk combine — register-prefetch. Grid (32,2,4), 256 thr. (R11)
// ---------------------------------------------------------------------------
__global__ __launch_bounds__(256) void statecombine_kernel(
    const float* __restrict__ Sb, const u16* __restrict__ Hb,
    u16* __restrict__ Hbf)
{
    __shared__ float sdec[32];
    const int h = blockIdx.y, b = blockIdx.z;
    const int e2 = blockIdx.x * 256 + threadIdx.x;
    if (threadIdx.x < 32)
        sdec[threadIdx.x] =
            __expf(Sb[(size_t)(b * LSEQ + threadIdx.x * 128 + 127) * 2 + h]);
    const size_t base2 = ((size_t)((b * 2 + h) * 32)) << 13;
    const unsigned int* src = (const unsigned int*)Hb;
    unsigned int* dst = (unsigned int*)Hbf;
    unsigned int v[32];
    #pragma unroll
    for (int c = 0; c < 32; c++)
        v[c] = src[base2 + ((size_t)c << 13) + e2];
    __syncthreads();
    float s0 = 0.f, s1 = 0.f;
    #pragma unroll
    for (int c = 0; c < 32; c++) {
        union { u16 u[2]; unsigned int q; } pk;
        pk.u[0] = f2h(s0); pk.u[1] = f2h(s1);
        dst[base2 + ((size_t)c << 13) + e2] = pk.q;
        float d = sdec[c];
        s0 = d * s0 + h2f((u16)(v[c] & 0xffffu));
        s1 = d * s1 + h2f((u16)(v[c] >> 16));
    }
}

// ---------------------------------------------------------------------------
// Per-head fused SSD (R11 version: Hin staged via LDS).
// Grid (32,2,4), 512 thr, ~145 KB LDS.
// ---------------------------------------------------------------------------
__global__ __launch_bounds__(512) void ssd_ph_kernel(
    const u16* __restrict__ zx16, const u16* __restrict__ Hbf,
    const float* __restrict__ dtb, const float* __restrict__ Sb,
    const float* __restrict__ cw, const float* __restrict__ cb,
    const float* __restrict__ Dp, u16* __restrict__ g16)
{
    __shared__ u16 raw[2560 * 8];     // staging -> Hin -> G
    __shared__ u16 XT[128 * 128];
    __shared__ u16 Btok[128 * 128];
    __shared__ u16 Ctok[128 * 128];
    __shared__ float sS[128], sdt[128];
    __shared__ float scw[3][128][4];
    __shared__ float scb[3][128];
    const int c = blockIdx.x, h = blockIdx.y, b = blockIdx.z;
    const int tid = threadIdx.x, wid = tid >> 6, lane = tid & 63;
    const int quad = lane >> 4, cl = lane & 15;
    const int tok0 = b * LSEQ + c * 128;
    const size_t blk = ((size_t)((b * 2 + h) * 32 + c)) << 14;
    for (int idx = tid; idx < 384; idx += 512) {
        int grp = idx >> 7, j = idx & 127;
        int ch = (grp == 0) ? (128 * h + j) : (grp == 1 ? 256 + j : 384 + j);
        float4 w4 = *(const float4*)&cw[ch * 4];
        scw[grp][j][0] = w4.x; scw[grp][j][1] = w4.y;
        scw[grp][j][2] = w4.z; scw[grp][j][3] = w4.w;
        scb[grp][j] = cb[ch];
    }
    if (tid < 128) {
        sS[tid] = Sb[(size_t)(tok0 + tid) * 2 + h];
        sdt[tid] = dtb[(size_t)(tok0 + tid) * 2 + h];
    }
    // ---- conv X -> XT
    #pragma unroll
    for (int i = 0; i < 5; i++) {
        int ck = i * 512 + tid;
        int r = ck >> 4; if (r > 130) r = 130;
        int cc = ck & 15;
        int tok = tok0 - 3 + r; if (tok < 0) tok = 0;
        async_lds16(zx16 + (size_t)tok * 768 + 256 + 128 * h + ((cc ^ (r & 15)) << 3),
                    (void*)(raw + (i * 512 + (tid & ~63)) * 8));
    }
    __syncthreads();
    if (c == 0 && tid < 48) *(uint4*)&raw[tid * 8] = make_uint4(0, 0, 0, 0);
    __syncthreads();
    #pragma unroll
    for (int it = 0; it < 4; it++) {
        int idx = it * 512 + tid;
        int s = idx & 127, pg = idx >> 7;
        f16x8 v[4];
        #pragma unroll
        for (int k = 0; k < 4; k++) {
            int rr = s + k;
            v[k] = *(const f16x8*)&raw[rr * 128 + ((pg ^ (rr & 15)) << 3)];
        }
        #pragma unroll
        for (int j = 0; j < 8; j++) {
            int p = pg * 8 + j;
            float o = scb[0][p] + (float)v[0][j] * scw[0][p][0]
                    + (float)v[1][j] * scw[0][p][1]
                    + (float)v[2][j] * scw[0][p][2]
                    + (float)v[3][j] * scw[0][p][3];
            XT[p * 128 + (((s >> 3) ^ (p & 15)) << 3) + (s & 7)] = f2h(silu_f(o));
        }
    }
    __syncthreads();
    // ---- conv B -> Btok (token-major)
    #pragma unroll
    for (int i = 0; i < 5; i++) {
        int ck = i * 512 + tid;
        int r = ck >> 4; if (r > 130) r = 130;
        int cc = ck & 15;
        int tok = tok0 - 3 + r; if (tok < 0) tok = 0;
        async_lds16(zx16 + (size_t)tok * 768 + 512 + ((cc ^ (r & 15)) << 3),
                    (void*)(raw + (i * 512 + (tid & ~63)) * 8));
    }
    __syncthreads();
    if (c == 0 && tid < 48) *(uint4*)&raw[tid * 8] = make_uint4(0, 0, 0, 0);
    __syncthreads();
    #pragma unroll
    for (int it = 0; it < 4; it++) {
        int idx = it * 512 + tid;
        int t = idx & 127, ng = idx >> 7;
        f16x8 v[4];
        #pragma unroll
        for (int k = 0; k < 4; k++) {
            int rr = t + k;
            v[k] = *(const f16x8*)&raw[rr * 128 + ((ng ^ (rr & 15)) << 3)];
        }
        union { u16 u[8]; uint4 q; } pk;
        #pragma unroll
        for (int j = 0; j < 8; j++) {
            int n = ng * 8 + j;
            float o = scb[1][n] + (float)v[0][j] * scw[1][n][0]
                    + (float)v[1][j] * scw[1][n][1]
                    + (float)v[2][j] * scw[1][n][2]
                    + (float)v[3][j] * scw[1][n][3];
            pk.u[j] = f2h(silu_f(o));
        }
        *(uint4*)&Btok[t * 128 + ((ng ^ (t & 15)) << 3)] = pk.q;
    }
    __syncthreads();
    // ---- conv C -> Ctok (token-major)
    #pragma unroll
    for (int i = 0; i < 5; i++) {
        int ck = i * 512 + tid;
        int r = ck >> 4; if (r > 130) r = 130;
        int cc = ck & 15;
        int tok = tok0 - 3 + r; if (tok < 0) tok = 0;
        async_lds16(zx16 + (size_t)tok * 768 + 640 + ((cc ^ (r & 15)) << 3),
                    (void*)(raw + (i * 512 + (tid & ~63)) * 8));
    }
    __syncthreads();
    if (c == 0 && tid < 48) *(uint4*)&raw[tid * 8] = make_uint4(0, 0, 0, 0);
    __syncthreads();
    #pragma unroll
    for (int it = 0; it < 4; it++) {
        int idx = it * 512 + tid;
        int t = idx & 127, ng = idx >> 7;
        f16x8 v[4];
        #pragma unroll
        for (int k = 0; k < 4; k++) {
            int rr = t + k;
            v[k] = *(const f16x8*)&raw[rr * 128 + ((ng ^ (rr & 15)) << 3)];
        }
        union { u16 u[8]; uint4 q; } pk;
        #pragma unroll
        for (int j = 0; j < 8; j++) {
            int n = ng * 8 + j;
            float o = scb[2][n] + (float)v[0][j] * scw[2][n][0]
                    + (float)v[1][j] * scw[2][n][1]
                    + (float)v[2][j] * scw[2][n][2]
                    + (float)v[3][j] * scw[2][n][3];
            pk.u[j] = f2h(silu_f(o));
        }
        *(uint4*)&Ctok[t * 128 + ((ng ^ (t & 15)) << 3)] = pk.q;
    }
    __syncthreads();   // raw free -> stage Hin
    #pragma unroll
    for (int i = 0; i < 4; i++) {
        int ck = i * 512 + tid;
        int r = ck >> 4, cc = ck & 15;
        async_lds16(Hbf + blk + (size_t)r * 128 + ((cc ^ (r & 15)) << 3),
                    (void*)(raw + (i * 512 + (tid & ~63)) * 8));
    }
    __syncthreads();
    // ---- phase 1: Y = C @ Hin^T ; scale by exp(S_t)
    const int wm = (wid >> 1) * 32, wn = (wid & 1) * 64;
    f32x4 acc[2][4];
    #pragma unroll
    for (int i = 0; i < 2; i++)
        #pragma unroll
        for (int j = 0; j < 4; j++) acc[i][j] = f32x4{0.f, 0.f, 0.f, 0.f};
    #pragma unroll
    for (int ks = 0; ks < 4; ks++) {
        f16x8 ca[2], hb[4];
        int kc = ks * 4 + quad;
        #pragma unroll
        for (int i = 0; i < 2; i++) {
            int r = wm + i * 16 + cl;
            ca[i] = *(const f16x8*)&Ctok[r * 128 + ((kc ^ (r & 15)) << 3)];
        }
        #pragma unroll
        for (int j = 0; j < 4; j++) {
            int r = wn + j * 16 + cl;
            hb[j] = *(const f16x8*)&raw[r * 128 + ((kc ^ (r & 15)) << 3)];
        }
        #pragma unroll
        for (int i = 0; i < 2; i++)
            #pragma unroll
            for (int j = 0; j < 4; j++)
                acc[i][j] = __builtin_amdgcn_mfma_f32_16x16x32_f16(
                    ca[i], hb[j], acc[i][j], 0, 0, 0);
    }
    #pragma unroll
    for (int i = 0; i < 2; i++)
        #pragma unroll
        for (int r = 0; r < 4; r++) {
            float e = __expf(sS[wm + i * 16 + quad * 4 + r]);
            #pragma unroll
            for (int j = 0; j < 4; j++) acc[i][j][r] *= e;
        }
    // ---- phase 2: S = C @ B^T (triangular skip)
    f32x4 sacc[2][4];
    #pragma unroll
    for (int i = 0; i < 2; i++)
        #pragma unroll
        for (int j = 0; j < 4; j++) sacc[i][j] = f32x4{0.f, 0.f, 0.f, 0.f};
    #pragma unroll
    for (int ks = 0; ks < 4; ks++) {
        f16x8 cs[2], bs[4];
        int kc = ks * 4 + quad;
        #pragma unroll
        for (int i2 = 0; i2 < 2; i2++) {
            int r = wm + i2 * 16 + cl;
            cs[i2] = *(const f16x8*)&Ctok[r * 128 + ((kc ^ (r & 15)) << 3)];
        }
        #pragma unroll
        for (int j = 0; j < 4; j++) {
            int r = wn + j * 16 + cl;
            bs[j] = *(const f16x8*)&Btok[r * 128 + ((kc ^ (r & 15)) << 3)];
        }
        #pragma unroll
        for (int i2 = 0; i2 < 2; i2++)
            #pragma unroll
            for (int j = 0; j < 4; j++)
                if (wm + i2 * 16 + 15 >= wn + j * 16)
                    sacc[i2][j] = __builtin_amdgcn_mfma_f32_16x16x32_f16(
                        cs[i2], bs[j], sacc[i2][j], 0, 0, 0);
    }
    __syncthreads();   // all reads of raw(Hin) done
    // ---- G = mask ∘ S ∘ exp(St-Ss) ∘ dt_s  -> raw (over Hin)
    #pragma unroll
    for (int i2 = 0; i2 < 2; i2++)
        #pragma unroll
        for (int r = 0; r < 4; r++) {
            int t = wm + i2 * 16 + quad * 4 + r;
            float Stv = sS[t];
            #pragma unroll
            for (int j = 0; j < 4; j++) {
                int s = wn + j * 16 + cl;
                float gv = 0.f;
                if (s <= t) gv = sacc[i2][j][r] * __expf(Stv - sS[s]) * sdt[s];
                raw[t * 128 + (((s >> 3) ^ (t & 15)) << 3) + (s & 7)] = f2h(gv);
            }
        }
    __syncthreads();
    // ---- phase 3: Y += G @ X
    #pragma unroll
    for (int ks = 0; ks < 4; ks++) {
        f16x8 ga[2], xb[4];
        int kc = ks * 4 + quad;
        #pragma unroll
        for (int i = 0; i < 2; i++) {
            int r = wm + i * 16 + cl;
            ga[i] = *(const f16x8*)&raw[r * 128 + ((kc ^ (r & 15)) << 3)];
        }
        #pragma unroll
        for (int j = 0; j < 4; j++) {
            int r = wn + j * 16 + cl;
            xb[j] = *(const f16x8*)&XT[r * 128 + ((kc ^ (r & 15)) << 3)];
        }
        #pragma unroll
        for (int i = 0; i < 2; i++)
            #pragma unroll
            for (int j = 0; j < 4; j++)
                acc[i][j] = __builtin_amdgcn_mfma_f32_16x16x32_f16(
                    ga[i], xb[j], acc[i][j], 0, 0, 0);
    }
    // ---- epilogue: g = (Y + D*x)*silu(z)
    const float dco = Dp[h];
    #pragma unroll
    for (int i = 0; i < 2; i++)
        #pragma unroll
        for (int r = 0; r < 4; r++) {
            int t = wm + i * 16 + quad * 4 + r;
            u16* row = g16 + (size_t)(tok0 + t) * 256 + h * 128;
            #pragma unroll
            for (int j = 0; j < 4; j++) {
                int p = wn + j * 16 + cl;
                float xv = h2f(XT[p * 128 + (((t >> 3) ^ (p & 15)) << 3) + (t & 7)]);
                float zv = h2f(zx16[(size_t)(tok0 + t) * 768 + h * 128 + p]);
                row[p] = f2h((acc[i][j][r] + dco * xv) * silu_f(zv));
            }
        }
}

// ---------------------------------------------------------------------------
// out-proj GEMM (K=256, N=128, BM=64): rstd sum-of-squares folded into the
// GEMM's staged-A tiles (no separate global pass); gnw folded into W cvt;
// + residual + RMS (+ fused final projection in mode 3).
// ---------------------------------------------------------------------------
__global__ __launch_bounds__(256) void gemm_outrms_kernel(
    const u16* __restrict__ A, const float* __restrict__ Wf,
    const float* __restrict__ gnw, const float* __restrict__ rmsw,
    u16* __restrict__ xp16, u16* __restrict__ hbuf16, u16* __restrict__ hn16,
    const float* __restrict__ out_wf, const float* __restrict__ out_b,
    float* __restrict__ dout, int mode)
{
    __shared__ u16 sA[64 * 64];
    __shared__ u16 sW[128 * 64];
    __shared__ float red[64][33];
    __shared__ float srstd[64];
    __shared__ float redp[64][5];
    __shared__ float rstdg[64];
    __shared__ u16 hn2[64 * 128];
    __shared__ u16 ow[64 * 128];
    const int K = 256;
    const int m0 = blockIdx.y * 64;
    const int tid = threadIdx.x, wid = tid >> 6, lane = tid & 63;
    const int wm = (wid >> 1) * 32, wn = (wid & 1) * 64;
    const int quad = lane >> 4, cl = lane & 15;
    f32x4 acc[2][4];
    #pragma unroll
    for (int i = 0; i < 2; i++)
        #pragma unroll
        for (int j = 0; j < 4; j++) acc[i][j] = f32x4{0.f, 0.f, 0.f, 0.f};

    float ssq = 0.f;   // per-thread partial sum-of-squares of g (row tid>>2)
    for (int k0 = 0; k0 < K; k0 += 64) {
        #pragma unroll
        for (int i = 0; i < 2; i++) {
            int ck = i * 256 + tid;
            int r = ck >> 3, cc = ck & 7;
            int csw = (cc ^ (r & 7)) << 3;
            async_lds16(A + (size_t)(m0 + r) * K + k0 + csw,
                        (void*)(sA + (i * 256 + (tid & ~63)) * 8));
        }
        #pragma unroll
        for (int i = 0; i < 4; i++) {
            int ck = i * 256 + tid;
            int r = ck >> 3, cc = ck & 7;
            int csw = (cc ^ (r & 7)) << 3;
            *(uint4*)&sW[ck * 8] = cvt8g(Wf + (size_t)r * K + k0 + csw,
                                         gnw + k0 + csw);
        }
        __syncthreads();
        {   // accumulate squares from staged A (swizzle permutes within row)
            int rr = tid >> 2, q = tid & 3;
            f16x8 v0 = *(const f16x8*)&sA[rr * 64 + q * 16];
            f16x8 v1 = *(const f16x8*)&sA[rr * 64 + q * 16 + 8];
            #pragma unroll
            for (int j = 0; j < 8; j++) {
                float a = (float)v0[j], bq = (float)v1[j];
                ssq += a * a + bq * bq;
            }
        }
        #pragma unroll
        for (int ks = 0; ks < 2; ks++) {
            f16x8 af[2], wv[4];
            int kc = ks * 4 + quad;
            #pragma unroll
            for (int i = 0; i < 2; i++) {
                int r = wm + i * 16 + cl;
                af[i] = *(const f16x8*)&sA[r * 64 + ((kc ^ (r & 7)) << 3)];
            }
            #pragma unroll
            for (int j = 0; j < 4; j++) {
                int r = wn + j * 16 + cl;
                wv[j] = *(const f16x8*)&sW[r * 64 + ((kc ^ (r & 7)) << 3)];
            }
            #pragma unroll
            for (int i = 0; i < 2; i++)
                #pragma unroll
                for (int j = 0; j < 4; j++)
                    acc[i][j] = __builtin_amdgcn_mfma_f32_16x16x32_f16(
                        af[i], wv[j], acc[i][j], 0, 0, 0);
        }
        __syncthreads();
    }
    redp[tid >> 2][tid & 3] = ssq;
    __syncthreads();
    if (tid < 64)
        rstdg[tid] = rsqrtf((redp[tid][0] + redp[tid][1] + redp[tid][2]
                             + redp[tid][3]) * (1.f / 256.f) + 1e-5f);
    __syncthreads();
    const int slot = (wid & 1) * 16 + cl;
    #pragma unroll
    for (int i = 0; i < 2; i++)
        #pragma unroll
        for (int r = 0; r < 4; r++) {
            int t = wm + i * 16 + quad * 4 + r;
            size_t ob = (size_t)(m0 + t) * 128;
            float rg = rstdg[t];
            float ssp = 0.f;
            #pragma unroll
            for (int j = 0; j < 4; j++) {
                int n = wn + j * 16 + cl;
                float v = acc[i][j][r] * rg + h2f(hbuf16[ob + n]);
                acc[i][j][r] = v;
                ssp += v * v;
            }
            red[t][slot] = ssp;
        }
    __syncthreads();
    if (tid < 64) {
        float s = 0.f;
        #pragma unroll
        for (int sl = 0; sl < 32; sl++) s += red[tid][sl];
        srstd[tid] = rsqrtf(s * (1.f / 128.f) + 1e-5f);
    }
    __syncthreads();
    #pragma unroll
    for (int i = 0; i < 2; i++)
        #pragma unroll
        for (int r = 0; r < 4; r++) {
            int t = wm + i * 16 + quad * 4 + r;
            size_t ob = (size_t)(m0 + t) * 128;
            float rstd = srstd[t];
            #pragma unroll
            for (int j = 0; j < 4; j++) {
                int n = wn + j * 16 + cl;
                float v = acc[i][j][r];
                float val = v * rstd * rmsw[n];
                if (mode == 1) {
                    hbuf16[ob + n] = f2h(v);
                    hn16[ob + n] = f2h(val);
                } else {
                    val += h2f(xp16[ob + n]);
                    hn2[t * 128 + (((n >> 3) ^ (t & 15)) << 3) + (n & 7)] = f2h(val);
                }
            }
        }
    if (mode == 1) return;
    #pragma unroll
    for (int i = 0; i < 4; i++) {
        int ck = i * 256 + tid;
        int rr = ck >> 4, cc = ck & 15;
        int csw = (cc ^ (rr & 15)) << 3;
        *(uint4*)&ow[ck * 8] = cvt8(out_wf + (size_t)rr * 128 + csw);
    }
    __syncthreads();
    const int wm4 = (wid >> 1) * 32, wn4 = (wid & 1) * 32;
    f32x4 acc2[2][2];
    #pragma unroll
    for (int i = 0; i < 2; i++)
        #pragma unroll
        for (int j = 0; j < 2; j++) acc2[i][j] = f32x4{0.f, 0.f, 0.f, 0.f};
    #pragma unroll
    for (int ks = 0; ks < 4; ks++) {
        f16x8 af2[2], wf2[2];
        int kc = ks * 4 + quad;
        #pragma unroll
        for (int i = 0; i < 2; i++) {
            int r = wm4 + i * 16 + cl;
            af2[i] = *(const f16x8*)&hn2[r * 128 + ((kc ^ (r & 15)) << 3)];
        }
        #pragma unroll
        for (int j = 0; j < 2; j++) {
            int rr = wn4 + j * 16 + cl;
            wf2[j] = *(const f16x8*)&ow[rr * 128 + ((kc ^ (rr & 15)) << 3)];
        }
        #pragma unroll
        for (int i = 0; i < 2; i++)
            #pragma unroll
            for (int j = 0; j < 2; j++)
                acc2[i][j] = __builtin_amdgcn_mfma_f32_16x16x32_f16(
                    af2[i], wf2[j], acc2[i][j], 0, 0, 0);
    }
    #pragma unroll
    for (int i = 0; i < 2; i++) {
        int m = m0 + wm4 + i * 16 + quad * 4;
        #pragma unroll
        for (int j = 0; j < 2; j++) {
            int n = wn4 + j * 16 + cl;
            float bv = out_b[n];
            #pragma unroll
            for (int r = 0; r < 4; r++)
                dout[(size_t)(m + r) * 64 + n] = acc2[i][j][r] + bv;
        }
    }
}

// ---------------------------------------------------------------------------
extern "C" void kernel_launch(void* const* d_in, const int* in_sizes, int n_in,
                              void* d_out, int out_size, void* d_ws, size_t ws_size,
                              hipStream_t stream)
{
    (void)in_sizes; (void)n_in; (void)out_size; (void)ws_size;
    const float* x       = (const float*)d_in[0];
    const float* in_w    = (const float*)d_in[1];
    const float* in_b    = (const float*)d_in[2];
    const float* out_w   = (const float*)d_in[3];
    const float* out_b   = (const float*)d_in[4];
    const float* l_rms_w = (const float*)d_in[5];
    const float* l_in_w  = (const float*)d_in[6];
    const float* conv_w  = (const float*)d_in[7];
    const float* conv_b  = (const float*)d_in[8];
    const float* dt_bias = (const float*)d_in[9];
    const float* A_log   = (const float*)d_in[10];
    const float* D_p     = (const float*)d_in[11];
    const float* gnorm_w = (const float*)d_in[12];
    const float* l_out_w = (const float*)d_in[13];
    const float* fnorm_w = (const float*)d_in[14];

    char* w = (char*)d_ws;
    u16*   xp16   = (u16*)(w);                  // 4.19 MB
    u16*   hbuf16 = (u16*)(w + 4194304);        // 4.19 MB
    u16*   hn16   = (u16*)(w + 8388608);        // 4.19 MB
    u16*   zx16   = (u16*)(w + 12582912);       // 25.17 MB
    float* dtb    = (float*)(w + 37748736);     // 131 KB
    float* Sb     = (float*)(w + 37879808);     // 131 KB
    u16*   Hb     = (u16*)(w + 38010880);       // 8.39 MB
    u16*   Hbf    = (u16*)(w + 46399488);       // 8.39 MB
    u16*   g16    = (u16*)(w + 54788096);       // 8.39 MB

    gemm_rms0_kernel<<<dim3(1, 256), 256, 0, stream>>>(
        x, in_w, in_b, l_rms_w, xp16, hbuf16, hn16);

    for (int i = 0; i < 2; i++) {
        gemm_inproj_kernel<<<dim3(7, 128), 256, 0, stream>>>(
            hn16, l_in_w + (size_t)i * 770 * 128, zx16, dtb, Sb,
            dt_bias + i * 2, A_log + i * 2);
        chunkstate_conv_kernel<<<dim3(32, 2, 4), 512, 0, stream>>>(
            zx16, conv_w + i * 2048, conv_b + i * 512, dtb, Sb, Hb);
        statecombine_kernel<<<dim3(32, 2, 4), 256, 0, stream>>>(Sb, Hb, Hbf);
        ssd_ph_kernel<<<dim3(32, 2, 4), 512, 0, stream>>>(
            zx16, Hbf, dtb, Sb, conv_w + i * 2048, conv_b + i * 512,
            D_p + i * 2, g16);
        gemm_outrms_kernel<<<dim3(1, 256), 256, 0, stream>>>(
            g16, l_out_w + (size_t)i * 128 * 256, gnorm_w + i * 256,
            (i == 0) ? (l_rms_w + 128) : fnorm_w, xp16, hbuf16, hn16,
            out_w, out_b, (float*)d_out, (i == 0) ? 1 : 3);
    }
}